// Round 6
// baseline (122.820 us; speedup 1.0000x reference)
//
#include <hip/hip_runtime.h>
#include <math.h>

#define N_NODES 10000
#define CAP 128       // max neighbors per row; P(deg>=128) ~ 1e-18 (Binom(1e4, .006))
#define SEG 625       // f32x4 per wave-segment (4 segments x 625 x 4 = 10000 cols)
#define SEGCAP 64     // max nnz per 2500-col segment; mean 15, P(>64) negligible
#define NCHUNK 10     // ceil(SEG/64)

typedef float f32x4 __attribute__((ext_vector_type(4)));

// ACT: 0=relu 1=silu 2=elu 3=leaky_relu 4=sigmoid
template <int ACT>
__device__ __forceinline__ float activate(float v) {
    if (ACT == 0) return fmaxf(v, 0.0f);
    if (ACT == 1) return v / (1.0f + __expf(-v));               // silu
    if (ACT == 2) return (v >= 0.0f) ? v : (__expf(v) - 1.0f);  // elu, alpha=1
    if (ACT == 3) return (v >= 0.0f) ? v : 0.01f * v;           // leaky relu
    return 1.0f / (1.0f + __expf(-v));                          // sigmoid
}

// ---------------------------------------------------------------------------
// One block (4 waves) per row, three phases:
//  P1: streaming scan of A[row, seg], 4-deep register ring. Per f32x4 chunk:
//      4 ballots; nonzero indices extracted by a wave-uniform scalar bit-pop
//      loop (work ~ nnz, not ~ cols). Lane 0 appends to LDS. No per-lane
//      prefix popcounts, no predicated-exec index math in the hot loop.
//  P2: per-wave gather of x[j, lane] over its own LDS index list (4-way
//      unrolled independent L2 loads) + coalesced CSR writeout.
//  P3: cross-wave reduce -> t1; wave 0: a1 = t1 @ W0, h1 = relu(a1).
// Deterministic: no atomics, fixed order everywhere (same append order as
// ballot-prefix version: per (chunk, component), ascending lane).
// ---------------------------------------------------------------------------
__global__ __launch_bounds__(256) void build_l1(
        const float* __restrict__ A, const float* __restrict__ x,
        const float* __restrict__ W0,
        int* __restrict__ counts, int* __restrict__ cols,
        float* __restrict__ t1, float* __restrict__ a1, float* __restrict__ h1) {
    __shared__ int   sidx[4][SEGCAP];
    __shared__ int   scnt[4];
    __shared__ float st[4][64];

    const int w    = threadIdx.x >> 6;
    const int lane = threadIdx.x & 63;
    const int row  = blockIdx.x;

    const f32x4* __restrict__ aseg =
        (const f32x4*)(A + (size_t)row * N_NODES) + w * SEG;

    // ---- P1: scan with 4-deep register-ring prefetch, light extraction ----
    f32x4 buf[4];
#pragma unroll
    for (int t = 0; t < 4; ++t)          // chunks 0..3 are full (255 < SEG)
        buf[t] = __builtin_nontemporal_load(&aseg[t * 64 + lane]);

    int cnt = 0;
#pragma unroll
    for (int t = 0; t < NCHUNK; ++t) {
        const f32x4 v = buf[t & 3];
        // refill this slot with chunk t+4 (compile-time bounds: unrolled)
        if (t + 4 < NCHUNK) {
            const int i4 = (t + 4) * 64 + lane;
            if (t + 4 == NCHUNK - 1) {   // partial tail chunk
                buf[t & 3] = (i4 < SEG) ? __builtin_nontemporal_load(&aseg[i4])
                                        : (f32x4)(0.0f);
            } else {
                buf[t & 3] = __builtin_nontemporal_load(&aseg[i4]);
            }
        }
#pragma unroll
        for (int c = 0; c < 4; ++c) {
            unsigned long long m = __ballot(v[c] != 0.0f);
            // wave-uniform scalar extraction: ~0.4 expected iterations
            while (m) {
                const int b = __ffsll((unsigned long long)m) - 1;
                m &= (m - 1ull);
                if (lane == 0 && cnt < SEGCAP)
                    sidx[w][cnt] = ((w * SEG + t * 64 + b) << 2) + c;
                ++cnt;
            }
        }
    }
    if (cnt > SEGCAP) cnt = SEGCAP;
    if (lane == 0) scnt[w] = cnt;
    __syncthreads();

    // ---- P2: per-wave x-gather over own segment list (indices in LDS) ----
    const int mycnt = scnt[w];
    float acc = 0.0f;
    {
        int k = 0;
        for (; k + 4 <= mycnt; k += 4) {
            const int j0 = sidx[w][k + 0];
            const int j1 = sidx[w][k + 1];
            const int j2 = sidx[w][k + 2];
            const int j3 = sidx[w][k + 3];
            const float v0 = x[j0 * 64 + lane];
            const float v1 = x[j1 * 64 + lane];
            const float v2 = x[j2 * 64 + lane];
            const float v3 = x[j3 * 64 + lane];
            acc += v0; acc += v1; acc += v2; acc += v3;
        }
        for (; k < mycnt; ++k)
            acc += x[sidx[w][k] * 64 + lane];
    }
    st[w][lane] = acc;

    // CSR writeout (coalesced, overlaps gather latency)
    const int c0 = scnt[0], c1 = scnt[1], c2 = scnt[2], c3 = scnt[3];
    const int offs4[4] = {0, c0, c0 + c1, c0 + c1 + c2};
    int total = c0 + c1 + c2 + c3;
    if (total > CAP) total = CAP;
    if (lane < mycnt) {
        const int p = offs4[w] + lane;
        if (p < CAP) cols[row * CAP + p] = sidx[w][lane];
    }
    if (threadIdx.x == 0) counts[row] = total;
    __syncthreads();

    // ---- P3: reduce t1 across waves; dense a1 = t1 @ W0 (64->16), relu ----
    if (w == 0) {
        const float tsum = st[0][lane] + st[1][lane] + st[2][lane] + st[3][lane];
        t1[row * 64 + lane] = tsum;
        st[0][lane] = tsum;
        const int o = lane & 15, q = lane >> 4;
        float a = 0.0f;
#pragma unroll
        for (int i = 0; i < 16; ++i) {
            const int ff = q * 16 + i;
            a += st[0][ff] * W0[ff * 16 + o];
        }
        a += __shfl_xor(a, 16);
        a += __shfl_xor(a, 32);
        if (q == 0) {
            a1[row * 16 + o] = a;
            h1[row * 16 + o] = activate<0>(a);
        }
    }
}

// ---------------------------------------------------------------------------
// Fused layer: t = gather-sum of h_in over adj(row); a = t @ W; h = act(a).
// One wave per row. f = lane % FIN (feature), g = lane / FIN (j-partition).
// ---------------------------------------------------------------------------
template <int FIN, int FOUT, int ACT>
__global__ __launch_bounds__(256) void layer_fused(
        const int* __restrict__ counts, const int* __restrict__ cols,
        const float* __restrict__ h_in, const float* __restrict__ W,
        float* __restrict__ t_out, float* __restrict__ a_out,
        float* __restrict__ h_out) {
    constexpr int G = 64 / FIN;
    __shared__ float tls[4][FIN];
    const int w    = threadIdx.x >> 6;
    const int lane = threadIdx.x & 63;
    const int row  = blockIdx.x * 4 + w;

    const int f = lane % FIN;
    const int g = lane / FIN;
    const int deg = counts[row];
    const int* __restrict__ crow = cols + row * CAP;

    float acc = 0.0f;
#pragma unroll 4
    for (int k = g; k < deg; k += G)
        acc += h_in[crow[k] * FIN + f];
#pragma unroll
    for (int off = FIN; off < 64; off <<= 1)
        acc += __shfl_xor(acc, off);
    if (g == 0) {
        t_out[row * FIN + f] = acc;
        tls[w][f] = acc;
    }
    __syncthreads();

    constexpr int NQ = 64 / FOUT;    // f-dim partitions
    constexpr int K  = FIN / NQ;     // f's per lane
    const int o = lane % FOUT, q = lane / FOUT;
    float a = 0.0f;
#pragma unroll
    for (int i = 0; i < K; ++i) {
        const int ff = q * K + i;
        a += tls[w][ff] * W[ff * FOUT + o];
    }
#pragma unroll
    for (int off = FOUT; off < 64; off <<= 1)
        a += __shfl_xor(a, off);
    if (q == 0) {
        a_out[row * FOUT + o] = a;
        h_out[row * FOUT + o] = activate<ACT>(a);
    }
}

// ---------------------------------------------------------------------------
extern "C" void kernel_launch(void* const* d_in, const int* in_sizes, int n_in,
                              void* d_out, int out_size, void* d_ws, size_t ws_size,
                              hipStream_t stream) {
    const float* x  = (const float*)d_in[0];   // 10000 x 64
    const float* A  = (const float*)d_in[1];   // 10000 x 10000
    const float* W0 = (const float*)d_in[2];   // 64 x 16
    const float* W1 = (const float*)d_in[3];   // 16 x 32
    const float* W2 = (const float*)d_in[4];   // 32 x 16
    const float* W3 = (const float*)d_in[5];   // 16 x 32
    const float* W4 = (const float*)d_in[6];   // 32 x 8

    float* out = (float*)d_out;
    // output layout: t1..t5, a1..a5, z (flattened, return order)
    float* t1 = out + 0;        // 10000*64
    float* t2 = out + 640000;   // 10000*16
    float* t3 = out + 800000;   // 10000*32
    float* t4 = out + 1120000;  // 10000*16
    float* t5 = out + 1280000;  // 10000*32
    float* a1 = out + 1600000;  // 10000*16
    float* a2 = out + 1760000;  // 10000*32
    float* a3 = out + 2080000;  // 10000*16
    float* a4 = out + 2240000;  // 10000*32
    float* a5 = out + 2560000;  // 10000*8
    float* z  = out + 2640000;  // 10000*8

    char* ws = (char*)d_ws;
    int*   counts = (int*)ws;                                         // 40 KB
    int*   cols   = (int*)(ws + 65536);                               // 5.12 MB
    float* hA     = (float*)(ws + 65536 + (size_t)N_NODES * CAP * 4); // 10000*32 f32
    float* hB     = hA + N_NODES * 32;

    // pass 1: one block per row — streaming scan (light extraction) + layer 1
    build_l1<<<N_NODES, 256, 0, stream>>>(A, x, W0, counts, cols, t1, a1, hA);

    // layers 2-5: 4 rows per block (one wave each)
    layer_fused<16, 32, 1><<<2500, 256, 0, stream>>>(counts, cols, hA, W1, t2, a2, hB);
    layer_fused<32, 16, 2><<<2500, 256, 0, stream>>>(counts, cols, hB, W2, t3, a3, hA);
    layer_fused<16, 32, 3><<<2500, 256, 0, stream>>>(counts, cols, hA, W3, t4, a4, hB);
    layer_fused<32, 8, 4><<<2500, 256, 0, stream>>>(counts, cols, hB, W4, t5, a5, z);
}